// Round 5
// baseline (734.880 us; speedup 1.0000x reference)
//
#include <hip/hip_runtime.h>
#include <hip/hip_bf16.h>
#include <math.h>

#define N_NODES 20000
#define N_EDGES 160000
#define D1 512    // layer-1 width: 4 heads * 128
#define D2 64     // layer-2 width: 1 head * 64
#define Y1W 2176  // q(0) k(512) v(1024) s(1536) P1(2048..2175)
#define Y2W 288   // q(0) k(64) v(128) s(192) P2(256..287)

typedef __attribute__((ext_vector_type(8))) short short8;
typedef __attribute__((ext_vector_type(4))) short short4v;
typedef __attribute__((ext_vector_type(4))) float floatx4;

__device__ __forceinline__ float bf2f(short u) {
    return __uint_as_float(((unsigned)(unsigned short)u) << 16);
}
__device__ __forceinline__ short f2bf(float f) {
    __hip_bfloat16 h = __float2bfloat16(f);
    return *(short*)&h;
}

// ---------------------------------------------------------------------------
// CSR build (by dst)
// ---------------------------------------------------------------------------
__global__ void hist_kernel(const int* __restrict__ ei, int* __restrict__ deg) {
    int e = blockIdx.x * blockDim.x + threadIdx.x;
    if (e < N_EDGES) atomicAdd(&deg[ei[N_EDGES + e]], 1);
}

__global__ void scan_kernel(const int* __restrict__ deg, int* __restrict__ rowptr) {
    const int NT = 1024;
    const int CH = (N_NODES + NT - 1) / NT;
    __shared__ int sums[NT];
    int t = threadIdx.x;
    int base = t * CH;
    int s = 0;
    for (int i = 0; i < CH; ++i) {
        int idx = base + i;
        if (idx < N_NODES) s += deg[idx];
    }
    sums[t] = s;
    __syncthreads();
    for (int off = 1; off < NT; off <<= 1) {
        int v = (t >= off) ? sums[t - off] : 0;
        __syncthreads();
        sums[t] += v;
        __syncthreads();
    }
    int run = (t > 0) ? sums[t - 1] : 0;
    for (int i = 0; i < CH; ++i) {
        int idx = base + i;
        if (idx < N_NODES) {
            rowptr[idx] = run;
            run += deg[idx];
        }
    }
    if (t == NT - 1) rowptr[N_NODES] = sums[NT - 1];
}

__global__ void fill_kernel(const int* __restrict__ ei, const int* __restrict__ rowptr,
                            int* __restrict__ cursor, int* __restrict__ srcs,
                            int* __restrict__ eid) {
    int e = blockIdx.x * blockDim.x + threadIdx.x;
    if (e < N_EDGES) {
        int src = ei[e];
        int dst = ei[N_EDGES + e];
        int p = rowptr[dst] + atomicAdd(&cursor[dst], 1);
        srcs[p] = src;
        eid[p] = e;
    }
}

// permute edge attrs into CSR order: eap[p*32+d] = ea[eid[p]*32+d]
__global__ void eaperm_kernel(const float* __restrict__ ea, const int* __restrict__ eid,
                              float* __restrict__ eap) {
    int idx = blockIdx.x * 256 + threadIdx.x;
    if (idx >= N_EDGES * 32) return;
    int p = idx >> 5, d = idx & 31;
    eap[idx] = ea[(size_t)eid[p] * 32 + d];
}

// ---------------------------------------------------------------------------
// Degree-descending schedule (counting sort, 64 bins)
// ---------------------------------------------------------------------------
__global__ void dsort_hist_kernel(const int* __restrict__ deg, int* __restrict__ bins) {
    int n = blockIdx.x * 256 + threadIdx.x;
    if (n < N_NODES) {
        int b = deg[n]; if (b > 63) b = 63;
        atomicAdd(&bins[63 - b], 1);
    }
}

__global__ void dsort_scan_kernel(const int* __restrict__ bins, int* __restrict__ binstart) {
    int t = threadIdx.x;  // one wave of 64
    int v = bins[t];
    int s = v;
    for (int off = 1; off < 64; off <<= 1) {
        int u = __shfl_up(s, off);
        if (t >= off) s += u;
    }
    binstart[t] = s - v;  // exclusive
}

__global__ void dsort_scatter_kernel(const int* __restrict__ deg, const int* __restrict__ binstart,
                                     int* __restrict__ bincur, int* __restrict__ dorder) {
    int n = blockIdx.x * 256 + threadIdx.x;
    if (n < N_NODES) {
        int b = deg[n]; if (b > 63) b = 63;
        b = 63 - b;
        int pos = binstart[b] + atomicAdd(&bincur[b], 1);
        dorder[pos] = n;
    }
}

// ---------------------------------------------------------------------------
// Weight prep: concatenated bf16 weights + fp32 bias, P-columns folded in.
// ---------------------------------------------------------------------------
__global__ void prep1_kernel(const float* __restrict__ Wq1, const float* __restrict__ bq1,
                             const float* __restrict__ Wk1, const float* __restrict__ bk1,
                             const float* __restrict__ Wv1, const float* __restrict__ bv1,
                             const float* __restrict__ Ws1, const float* __restrict__ bs1,
                             const float* __restrict__ We1,
                             __hip_bfloat16* __restrict__ W1b, float* __restrict__ b1) {
    int j = blockIdx.x, t = threadIdx.x;  // t = k in [0,128)
    if (j < 2048) {
        int sel = j >> 9, r = j & 511;
        const float* W = sel == 0 ? Wq1 : sel == 1 ? Wk1 : sel == 2 ? Wv1 : Ws1;
        const float* bs = sel == 0 ? bq1 : sel == 1 ? bk1 : sel == 2 ? bv1 : bs1;
        W1b[(size_t)j * 128 + t] = __float2bfloat16(W[(size_t)r * 128 + t]);
        if (t == 0) b1[j] = bs[r];
    } else {
        int hd = j - 2048, h = hd >> 5, d = hd & 31;
        float acc = 0.f;
        for (int c = 0; c < 128; ++c)
            acc += Wq1[(size_t)(h * 128 + c) * 128 + t] * We1[(size_t)(h * 128 + c) * 32 + d];
        W1b[(size_t)j * 128 + t] = __float2bfloat16(acc);
        if (t == 0) {
            float b = 0.f;
            for (int c = 0; c < 128; ++c) b += bq1[h * 128 + c] * We1[(size_t)(h * 128 + c) * 32 + d];
            b1[j] = b;
        }
    }
}

__global__ void prep2_kernel(const float* __restrict__ Wq2, const float* __restrict__ bq2,
                             const float* __restrict__ Wk2, const float* __restrict__ bk2,
                             const float* __restrict__ Wv2, const float* __restrict__ bv2,
                             const float* __restrict__ Ws2, const float* __restrict__ bs2,
                             const float* __restrict__ We2,
                             __hip_bfloat16* __restrict__ W2b, float* __restrict__ b2) {
    int j = blockIdx.x, t = threadIdx.x;
    for (int kk = t; kk < 512; kk += 256) {
        float val;
        if (j < 256) {
            int sel = j >> 6, r = j & 63;
            const float* W = sel == 0 ? Wq2 : sel == 1 ? Wk2 : sel == 2 ? Wv2 : Ws2;
            val = W[(size_t)r * 512 + kk];
        } else {
            int d = j - 256;
            float acc = 0.f;
            for (int c = 0; c < 64; ++c) acc += Wq2[(size_t)c * 512 + kk] * We2[c * 32 + d];
            val = acc;
        }
        W2b[(size_t)j * 512 + kk] = __float2bfloat16(val);
    }
    if (t == 0) {
        if (j < 256) {
            int sel = j >> 6, r = j & 63;
            const float* bs = sel == 0 ? bq2 : sel == 1 ? bk2 : sel == 2 ? bv2 : bs2;
            b2[j] = bs[r];
        } else {
            int d = j - 256;
            float b = 0.f;
            for (int c = 0; c < 64; ++c) b += bq2[c] * We2[c * 32 + d];
            b2[j] = b;
        }
    }
}

// ---------------------------------------------------------------------------
// MFMA GEMM: C[M,N] = A[M,K] @ B[N,K]^T + bias.  128x128 tile, 4 waves (2x2),
// k-slot XOR swizzle -> conflict-free ds_read_b128.
// ---------------------------------------------------------------------------
template <int K, bool A_F32, bool OUT_BF16>
__global__ __launch_bounds__(256) void gemm_bt(const void* __restrict__ Ap,
                                               const __hip_bfloat16* __restrict__ B,
                                               const float* __restrict__ bias,
                                               void* __restrict__ Cout,
                                               int M, int N, int tiles_n) {
    __shared__ char lds[65536];
    char* ldsA = lds;
    char* ldsB = lds + 32768;
    int tid = threadIdx.x;
    int bm = blockIdx.x / tiles_n, bn = blockIdx.x % tiles_n;
    int w = tid >> 6, lane = tid & 63;
    int wr = (w >> 1) * 64, wc = (w & 1) * 64;
    int lrow = lane & 15, lk = lane >> 4;
    floatx4 acc[4][4] = {};

    for (int kt = 0; kt < K / 128; ++kt) {
        if (kt) __syncthreads();
        #pragma unroll
        for (int it = 0; it < 8; ++it) {
            int s = it * 256 + tid;
            int row = s >> 4, kslot = s & 15;
            int phys = ((kslot ^ (row & 15)) << 4);
            int gr = bm * 128 + row;
            if (gr > M - 1) gr = M - 1;
            short8 va;
            if (A_F32) {
                const float* Af = (const float*)Ap;
                float4 x0 = *(const float4*)(Af + (size_t)gr * K + kt * 128 + kslot * 8);
                float4 x1 = *(const float4*)(Af + (size_t)gr * K + kt * 128 + kslot * 8 + 4);
                va[0] = f2bf(x0.x); va[1] = f2bf(x0.y); va[2] = f2bf(x0.z); va[3] = f2bf(x0.w);
                va[4] = f2bf(x1.x); va[5] = f2bf(x1.y); va[6] = f2bf(x1.z); va[7] = f2bf(x1.w);
            } else {
                const __hip_bfloat16* Ab = (const __hip_bfloat16*)Ap;
                va = *(const short8*)(Ab + (size_t)gr * K + kt * 128 + kslot * 8);
            }
            *(short8*)(ldsA + row * 256 + phys) = va;
            int gc = bn * 128 + row;
            if (gc > N - 1) gc = N - 1;
            short8 vb = *(const short8*)(B + (size_t)gc * K + kt * 128 + kslot * 8);
            *(short8*)(ldsB + row * 256 + phys) = vb;
        }
        __syncthreads();
        #pragma unroll
        for (int ks = 0; ks < 4; ++ks) {
            short8 af[4], bfr[4];
            #pragma unroll
            for (int m = 0; m < 4; ++m) {
                int r = wr + m * 16 + lrow;
                int kslot = ks * 4 + lk;
                af[m] = *(const short8*)(ldsA + r * 256 + ((kslot ^ (r & 15)) << 4));
            }
            #pragma unroll
            for (int n = 0; n < 4; ++n) {
                int c = wc + n * 16 + lrow;
                int kslot = ks * 4 + lk;
                bfr[n] = *(const short8*)(ldsB + c * 256 + ((kslot ^ (c & 15)) << 4));
            }
            #pragma unroll
            for (int m = 0; m < 4; ++m)
                #pragma unroll
                for (int n = 0; n < 4; ++n)
                    acc[m][n] = __builtin_amdgcn_mfma_f32_16x16x32_bf16(af[m], bfr[n], acc[m][n], 0, 0, 0);
        }
    }

    #pragma unroll
    for (int m = 0; m < 4; ++m) {
        #pragma unroll
        for (int j = 0; j < 4; ++j) {
            int r = bm * 128 + wr + m * 16 + lk * 4 + j;
            if (r >= M) continue;
            #pragma unroll
            for (int n = 0; n < 4; ++n) {
                int gc = bn * 128 + wc + n * 16 + lrow;
                if (gc >= N) continue;
                float v = acc[m][n][j] + bias[gc];
                if (OUT_BF16)
                    ((__hip_bfloat16*)Cout)[(size_t)r * N + gc] = __float2bfloat16(v);
                else
                    ((float*)Cout)[(size_t)r * N + gc] = v;
            }
        }
    }
}

// ---------------------------------------------------------------------------
// Layer-1 attention: TWO waves per dst (head pairs). Wave handles 2 heads of
// 128 ch; lane owns 4 ch of one head (32-lane groups); softmax reduce via
// xor-shfl 1..16. Edge loop 2-deep. dst order = degree-descending.
// ---------------------------------------------------------------------------
__global__ __launch_bounds__(256) void attn1_kernel(
    const __hip_bfloat16* __restrict__ Y1, const float* __restrict__ eap,
    const int* __restrict__ srcs, const int* __restrict__ rowptr,
    const int* __restrict__ dorder,
    const float* __restrict__ We1, __hip_bfloat16* __restrict__ hb) {
    int wid = threadIdx.x >> 6, lane = threadIdx.x & 63;
    int wslot = blockIdx.x * 4 + wid;
    if (wslot >= 2 * N_NODES) return;
    int dst = dorder[wslot >> 1];
    int pair = wslot & 1;
    int hh = pair * 2 + (lane >> 5);      // absolute head 0..3
    int cloc = (lane & 31) * 4;           // channel-in-head base (4 ch/lane)
    int c0 = hh * 128 + cloc;             // absolute channel base
    int d = lane & 31;                    // edge-dim slot owned by lane
    const size_t rowb = (size_t)dst * Y1W;

    short4v qv = *(const short4v*)(Y1 + rowb + c0);
    float q0 = bf2f(qv[0]), q1 = bf2f(qv[1]), q2 = bf2f(qv[2]), q3 = bf2f(qv[3]);
    float pv = __bfloat162float(Y1[rowb + 2048 + hh * 32 + d]);

    float accv[4] = {0.f, 0.f, 0.f, 0.f};
    float t = 0.f, denom = 0.f;
    int beg = rowptr[dst], end = rowptr[dst + 1];

    auto proc = [&](short4v kk, short4v vv, float eav) {
        float s = q0 * bf2f(kk[0]) + q1 * bf2f(kk[1])
                + q2 * bf2f(kk[2]) + q3 * bf2f(kk[3]) + pv * eav;
        s += __shfl_xor(s, 1);
        s += __shfl_xor(s, 2);
        s += __shfl_xor(s, 4);
        s += __shfl_xor(s, 8);
        s += __shfl_xor(s, 16);
        float wgt = __expf(s * 0.08838834764831845f);  // 1/sqrt(128)
        denom += wgt;
        accv[0] += wgt * bf2f(vv[0]); accv[1] += wgt * bf2f(vv[1]);
        accv[2] += wgt * bf2f(vv[2]); accv[3] += wgt * bf2f(vv[3]);
        t += wgt * eav;
    };

    int i = beg;
    for (; i + 2 <= end; i += 2) {
        int sA = srcs[i], sB = srcs[i + 1];
        const size_t ra = (size_t)sA * Y1W, rb2 = (size_t)sB * Y1W;
        short4v kA = *(const short4v*)(Y1 + ra + 512 + c0);
        short4v kB = *(const short4v*)(Y1 + rb2 + 512 + c0);
        short4v vA = *(const short4v*)(Y1 + ra + 1024 + c0);
        short4v vB = *(const short4v*)(Y1 + rb2 + 1024 + c0);
        float eA = eap[(size_t)i * 32 + d];
        float eB = eap[(size_t)(i + 1) * 32 + d];
        proc(kA, vA, eA);
        proc(kB, vB, eB);
    }
    if (i < end) {
        int sA = srcs[i];
        const size_t ra = (size_t)sA * Y1W;
        short4v kA = *(const short4v*)(Y1 + ra + 512 + c0);
        short4v vA = *(const short4v*)(Y1 + ra + 1024 + c0);
        proc(kA, vA, eap[(size_t)i * 32 + d]);
    }

    // gather this head's t[0..31] from the 32-lane group
    float tt[32];
    int gbase = lane & 32;
    #pragma unroll
    for (int dd = 0; dd < 32; ++dd) tt[dd] = __shfl(t, gbase + dd);
    float inv = (end > beg) ? 1.f / denom : 0.f;
    short4v sv = *(const short4v*)(Y1 + rowb + 1536 + c0);
    short4v hv;
    #pragma unroll
    for (int j = 0; j < 4; ++j) {
        const float4* wr = (const float4*)(We1 + (size_t)(c0 + j) * 32);
        float sum = 0.f;
        #pragma unroll
        for (int d4 = 0; d4 < 8; ++d4) {
            float4 w4 = wr[d4];
            sum += w4.x * tt[d4 * 4] + w4.y * tt[d4 * 4 + 1]
                 + w4.z * tt[d4 * 4 + 2] + w4.w * tt[d4 * 4 + 3];
        }
        float v = (accv[j] + sum) * inv + bf2f(sv[j]);
        hv[j] = f2bf(v > 0.f ? v : 0.f);
    }
    *(short4v*)(hb + (size_t)dst * D1 + c0) = hv;
}

// ---------------------------------------------------------------------------
// Layer-2 attention: one wave per dst, 1 head, C=64; Y2 is bf16 (stride 288).
// ---------------------------------------------------------------------------
__global__ __launch_bounds__(256) void attn2_kernel(
    const __hip_bfloat16* __restrict__ Y2, const float* __restrict__ eap,
    const int* __restrict__ srcs, const int* __restrict__ rowptr,
    const int* __restrict__ dorder,
    const float* __restrict__ We2, float* __restrict__ zout) {
    int wid = threadIdx.x >> 6, lane = threadIdx.x & 63;
    int slot = blockIdx.x * 4 + wid;
    if (slot >= N_NODES) return;
    int dst = dorder[slot];
    const size_t rowb = (size_t)dst * Y2W;
    float qv = __bfloat162float(Y2[rowb + lane]);
    float pv = (lane < 32) ? __bfloat162float(Y2[rowb + 256 + lane]) : 0.f;
    float acc = 0.f, t = 0.f, denom = 0.f;
    int beg = rowptr[dst], end = rowptr[dst + 1];

    auto proc = [&](short kb, short vb, float eav) {
        float s = qv * bf2f(kb) + pv * eav;
        s += __shfl_xor(s, 1);
        s += __shfl_xor(s, 2);
        s += __shfl_xor(s, 4);
        s += __shfl_xor(s, 8);
        s += __shfl_xor(s, 16);
        s += __shfl_xor(s, 32);
        float wgt = __expf(s * 0.125f);  // 1/sqrt(64)
        denom += wgt;
        acc += wgt * bf2f(vb);
        t += wgt * eav;
    };

    int i = beg;
    for (; i + 2 <= end; i += 2) {
        int sA = srcs[i], sB = srcs[i + 1];
        const size_t ra = (size_t)sA * Y2W, rb2 = (size_t)sB * Y2W;
        short kA = *(const short*)(Y2 + ra + 64 + lane);
        short kB = *(const short*)(Y2 + rb2 + 64 + lane);
        short vA = *(const short*)(Y2 + ra + 128 + lane);
        short vB = *(const short*)(Y2 + rb2 + 128 + lane);
        float eA = (lane < 32) ? eap[(size_t)i * 32 + lane] : 0.f;
        float eB = (lane < 32) ? eap[(size_t)(i + 1) * 32 + lane] : 0.f;
        proc(kA, vA, eA);
        proc(kB, vB, eB);
    }
    if (i < end) {
        int sA = srcs[i];
        const size_t ra = (size_t)sA * Y2W;
        proc(*(const short*)(Y2 + ra + 64 + lane),
             *(const short*)(Y2 + ra + 128 + lane),
             (lane < 32) ? eap[(size_t)i * 32 + lane] : 0.f);
    }

    float tt[32];
    #pragma unroll
    for (int dd = 0; dd < 32; ++dd) tt[dd] = __shfl(t, dd);
    float inv = (end > beg) ? 1.f / denom : 0.f;
    const float4* wr = (const float4*)(We2 + (size_t)lane * 32);
    float sum = 0.f;
    #pragma unroll
    for (int d4 = 0; d4 < 8; ++d4) {
        float4 w4 = wr[d4];
        sum += w4.x * tt[d4 * 4] + w4.y * tt[d4 * 4 + 1]
             + w4.z * tt[d4 * 4 + 2] + w4.w * tt[d4 * 4 + 3];
    }
    zout[(size_t)dst * D2 + lane] =
        (acc + sum) * inv + __bfloat162float(Y2[rowb + 192 + lane]);
}

// ---------------------------------------------------------------------------
extern "C" void kernel_launch(void* const* d_in, const int* in_sizes, int n_in,
                              void* d_out, int out_size, void* d_ws, size_t ws_size,
                              hipStream_t stream) {
    const float* x   = (const float*)d_in[0];
    const int*   ei  = (const int*)d_in[1];
    const float* ea  = (const float*)d_in[2];
    const float* Wq1 = (const float*)d_in[3];  const float* bq1 = (const float*)d_in[4];
    const float* Wk1 = (const float*)d_in[5];  const float* bk1 = (const float*)d_in[6];
    const float* Wv1 = (const float*)d_in[7];  const float* bv1 = (const float*)d_in[8];
    const float* We1 = (const float*)d_in[9];
    const float* Ws1 = (const float*)d_in[10]; const float* bs1 = (const float*)d_in[11];
    const float* Wq2 = (const float*)d_in[12]; const float* bq2 = (const float*)d_in[13];
    const float* Wk2 = (const float*)d_in[14]; const float* bk2 = (const float*)d_in[15];
    const float* Wv2 = (const float*)d_in[16]; const float* bv2 = (const float*)d_in[17];
    const float* We2 = (const float*)d_in[18];
    const float* Ws2 = (const float*)d_in[19]; const float* bs2 = (const float*)d_in[20];
    float* zout = (float*)d_out;

    char* wsb = (char*)d_ws;
    size_t off = 0;
    auto alloc = [&](size_t bytes) -> void* {
        void* p = wsb + off;
        off += (bytes + 255) & ~(size_t)255;
        return p;
    };
    __hip_bfloat16* Y1  = (__hip_bfloat16*)alloc((size_t)N_NODES * Y1W * 2);
    __hip_bfloat16* hbb = (__hip_bfloat16*)alloc((size_t)N_NODES * D1 * 2);
    __hip_bfloat16* Y2  = (__hip_bfloat16*)alloc((size_t)N_NODES * Y2W * 2);
    __hip_bfloat16* W1b = (__hip_bfloat16*)alloc((size_t)2176 * 128 * 2);
    float*          b1  = (float*)alloc(2176 * 4);
    __hip_bfloat16* W2b = (__hip_bfloat16*)alloc((size_t)288 * 512 * 2);
    float*          b2  = (float*)alloc(288 * 4);
    int* deg    = (int*)alloc((size_t)N_NODES * 4);
    int* cursor = (int*)alloc((size_t)N_NODES * 4);
    int* rowptr = (int*)alloc((size_t)(N_NODES + 1) * 4);
    int* srcs   = (int*)alloc((size_t)N_EDGES * 4);
    int* eid    = (int*)alloc((size_t)N_EDGES * 4);
    float* eap  = (float*)alloc((size_t)N_EDGES * 32 * 4);
    int* bins    = (int*)alloc(64 * 4);
    int* binstart= (int*)alloc(64 * 4);
    int* bincur  = (int*)alloc(64 * 4);
    int* dorder  = (int*)alloc((size_t)N_NODES * 4);

    hipMemsetAsync(deg, 0, (size_t)N_NODES * 4, stream);
    hipMemsetAsync(cursor, 0, (size_t)N_NODES * 4, stream);
    hipMemsetAsync(bins, 0, 64 * 4, stream);
    hipMemsetAsync(bincur, 0, 64 * 4, stream);

    // CSR build + edge-attr permutation + degree-descending schedule
    hist_kernel<<<(N_EDGES + 255) / 256, 256, 0, stream>>>(ei, deg);
    scan_kernel<<<1, 1024, 0, stream>>>(deg, rowptr);
    fill_kernel<<<(N_EDGES + 255) / 256, 256, 0, stream>>>(ei, rowptr, cursor, srcs, eid);
    eaperm_kernel<<<(N_EDGES * 32 + 255) / 256, 256, 0, stream>>>(ea, eid, eap);
    dsort_hist_kernel<<<(N_NODES + 255) / 256, 256, 0, stream>>>(deg, bins);
    dsort_scan_kernel<<<1, 64, 0, stream>>>(bins, binstart);
    dsort_scatter_kernel<<<(N_NODES + 255) / 256, 256, 0, stream>>>(deg, binstart, bincur, dorder);

    // weight prep (P-columns folded in)
    prep1_kernel<<<2176, 128, 0, stream>>>(Wq1, bq1, Wk1, bk1, Wv1, bv1, Ws1, bs1,
                                           We1, W1b, b1);
    prep2_kernel<<<288, 256, 0, stream>>>(Wq2, bq2, Wk2, bk2, Wv2, bv2, Ws2, bs2,
                                          We2, W2b, b2);

    // layer 1: Y1 = x @ W1b^T + b1   (M=20000, N=2176, K=128)
    int tiles_m = (N_NODES + 127) / 128;  // 157
    gemm_bt<128, true, true><<<tiles_m * 17, 256, 0, stream>>>(
        (const void*)x, W1b, b1, (void*)Y1, N_NODES, Y1W, 17);
    attn1_kernel<<<(2 * N_NODES + 3) / 4, 256, 0, stream>>>(Y1, eap, srcs, rowptr,
                                                            dorder, We1, hbb);

    // layer 2: Y2 = h @ W2b^T + b2   (M=20000, N=288, K=512), bf16 out
    gemm_bt<512, false, true><<<tiles_m * 3, 256, 0, stream>>>(
        (const void*)hbb, W2b, b2, (void*)Y2, N_NODES, Y2W, 3);
    attn2_kernel<<<(N_NODES + 3) / 4, 256, 0, stream>>>(Y2, eap, srcs, rowptr,
                                                        dorder, We2, zout);
}

// Round 7
// 591.805 us; speedup vs baseline: 1.2418x; 1.2418x over previous
//
#include <hip/hip_runtime.h>
#include <hip/hip_bf16.h>
#include <math.h>

#define N_NODES 20000
#define N_EDGES 160000
#define D1 512    // layer-1 width: 4 heads * 128
#define D2 64     // layer-2 width: 1 head * 64
#define Y1W 2176  // q(0) k(512) v(1024) s(1536) P1(2048..2175)
#define Y2W 288   // q(0) k(64) v(128) s(192) P2(256..287)

typedef __attribute__((ext_vector_type(8))) short short8;
typedef __attribute__((ext_vector_type(4))) float floatx4;

__device__ __forceinline__ float bf2f(short u) {
    return __uint_as_float(((unsigned)(unsigned short)u) << 16);
}
__device__ __forceinline__ short f2bf(float f) {
    __hip_bfloat16 h = __float2bfloat16(f);
    return *(short*)&h;
}
__device__ __forceinline__ float i8tof(unsigned int u, int c) {
    return (float)(signed char)((u >> (8 * c)) & 255u);
}
__device__ __forceinline__ unsigned int q8(float x, float inv) {
    float t = x * inv;
    t = fminf(fmaxf(t, -127.f), 127.f);
    return (unsigned int)(__float2int_rn(t)) & 255u;
}

// ---------------------------------------------------------------------------
// CSR build (by dst)
// ---------------------------------------------------------------------------
__global__ void hist_kernel(const int* __restrict__ ei, int* __restrict__ deg) {
    int e = blockIdx.x * blockDim.x + threadIdx.x;
    if (e < N_EDGES) atomicAdd(&deg[ei[N_EDGES + e]], 1);
}

__global__ void scan_kernel(const int* __restrict__ deg, int* __restrict__ rowptr) {
    const int NT = 1024;
    const int CH = (N_NODES + NT - 1) / NT;
    __shared__ int sums[NT];
    int t = threadIdx.x;
    int base = t * CH;
    int s = 0;
    for (int i = 0; i < CH; ++i) {
        int idx = base + i;
        if (idx < N_NODES) s += deg[idx];
    }
    sums[t] = s;
    __syncthreads();
    for (int off = 1; off < NT; off <<= 1) {
        int v = (t >= off) ? sums[t - off] : 0;
        __syncthreads();
        sums[t] += v;
        __syncthreads();
    }
    int run = (t > 0) ? sums[t - 1] : 0;
    for (int i = 0; i < CH; ++i) {
        int idx = base + i;
        if (idx < N_NODES) {
            rowptr[idx] = run;
            run += deg[idx];
        }
    }
    if (t == NT - 1) rowptr[N_NODES] = sums[NT - 1];
}

__global__ void fill_kernel(const int* __restrict__ ei, const int* __restrict__ rowptr,
                            int* __restrict__ cursor, int* __restrict__ srcs,
                            int* __restrict__ eid) {
    int e = blockIdx.x * blockDim.x + threadIdx.x;
    if (e < N_EDGES) {
        int src = ei[e];
        int dst = ei[N_EDGES + e];
        int p = rowptr[dst] + atomicAdd(&cursor[dst], 1);
        srcs[p] = src;
        eid[p] = e;
    }
}

// permute edge attrs into CSR order: eap[p*32+d] = ea[eid[p]*32+d]
__global__ void eaperm_kernel(const float* __restrict__ ea, const int* __restrict__ eid,
                              float* __restrict__ eap) {
    int idx = blockIdx.x * 256 + threadIdx.x;
    if (idx >= N_EDGES * 32) return;
    int p = idx >> 5, d = idx & 31;
    eap[idx] = ea[(size_t)eid[p] * 32 + d];
}

// ---------------------------------------------------------------------------
// Weight prep: concatenated bf16 weights + fp32 bias, P-columns folded in.
// ---------------------------------------------------------------------------
__global__ void prep1_kernel(const float* __restrict__ Wq1, const float* __restrict__ bq1,
                             const float* __restrict__ Wk1, const float* __restrict__ bk1,
                             const float* __restrict__ Wv1, const float* __restrict__ bv1,
                             const float* __restrict__ Ws1, const float* __restrict__ bs1,
                             const float* __restrict__ We1,
                             __hip_bfloat16* __restrict__ W1b, float* __restrict__ b1) {
    int j = blockIdx.x, t = threadIdx.x;  // t = k in [0,128)
    if (j < 2048) {
        int sel = j >> 9, r = j & 511;
        const float* W = sel == 0 ? Wq1 : sel == 1 ? Wk1 : sel == 2 ? Wv1 : Ws1;
        const float* bs = sel == 0 ? bq1 : sel == 1 ? bk1 : sel == 2 ? bv1 : bs1;
        W1b[(size_t)j * 128 + t] = __float2bfloat16(W[(size_t)r * 128 + t]);
        if (t == 0) b1[j] = bs[r];
    } else {
        int hd = j - 2048, h = hd >> 5, d = hd & 31;
        float acc = 0.f;
        for (int c = 0; c < 128; ++c)
            acc += Wq1[(size_t)(h * 128 + c) * 128 + t] * We1[(size_t)(h * 128 + c) * 32 + d];
        W1b[(size_t)j * 128 + t] = __float2bfloat16(acc);
        if (t == 0) {
            float b = 0.f;
            for (int c = 0; c < 128; ++c) b += bq1[h * 128 + c] * We1[(size_t)(h * 128 + c) * 32 + d];
            b1[j] = b;
        }
    }
}

__global__ void prep2_kernel(const float* __restrict__ Wq2, const float* __restrict__ bq2,
                             const float* __restrict__ Wk2, const float* __restrict__ bk2,
                             const float* __restrict__ Wv2, const float* __restrict__ bv2,
                             const float* __restrict__ Ws2, const float* __restrict__ bs2,
                             const float* __restrict__ We2,
                             __hip_bfloat16* __restrict__ W2b, float* __restrict__ b2) {
    int j = blockIdx.x, t = threadIdx.x;
    for (int kk = t; kk < 512; kk += 256) {
        float val;
        if (j < 256) {
            int sel = j >> 6, r = j & 63;
            const float* W = sel == 0 ? Wq2 : sel == 1 ? Wk2 : sel == 2 ? Wv2 : Ws2;
            val = W[(size_t)r * 512 + kk];
        } else {
            int d = j - 256;
            float acc = 0.f;
            for (int c = 0; c < 64; ++c) acc += Wq2[(size_t)c * 512 + kk] * We2[c * 32 + d];
            val = acc;
        }
        W2b[(size_t)j * 512 + kk] = __float2bfloat16(val);
    }
    if (t == 0) {
        if (j < 256) {
            int sel = j >> 6, r = j & 63;
            const float* bs = sel == 0 ? bq2 : sel == 1 ? bk2 : sel == 2 ? bv2 : bs2;
            b2[j] = bs[r];
        } else {
            int d = j - 256;
            float b = 0.f;
            for (int c = 0; c < 64; ++c) b += bq2[c] * We2[c * 32 + d];
            b2[j] = b;
        }
    }
}

// ---------------------------------------------------------------------------
// int8 per-row-scale k/v pack.
// Layer 1: one wave per node; lane owns 8 k-ch + 8 v-ch.
//   KV1[n][0..512) = k int8, [512..1024) = v int8; sc1[n] = (kmax, vmax)/127.
// ---------------------------------------------------------------------------
__global__ __launch_bounds__(256) void kvpack1_kernel(
    const __hip_bfloat16* __restrict__ Y1, signed char* __restrict__ KV,
    float2* __restrict__ sc) {
    int wid = threadIdx.x >> 6, lane = threadIdx.x & 63;
    int n = blockIdx.x * 4 + wid;
    if (n >= N_NODES) return;
    const __hip_bfloat16* row = Y1 + (size_t)n * Y1W;
    short8 kv = *(const short8*)(row + 512 + lane * 8);
    short8 vv = *(const short8*)(row + 1024 + lane * 8);
    float kf[8], vf[8];
    float kmax = 0.f, vmax = 0.f;
    #pragma unroll
    for (int j = 0; j < 8; ++j) {
        kf[j] = bf2f(kv[j]); kmax = fmaxf(kmax, fabsf(kf[j]));
        vf[j] = bf2f(vv[j]); vmax = fmaxf(vmax, fabsf(vf[j]));
    }
    #pragma unroll
    for (int off = 1; off < 64; off <<= 1) {
        kmax = fmaxf(kmax, __shfl_xor(kmax, off));
        vmax = fmaxf(vmax, __shfl_xor(vmax, off));
    }
    float kinv = kmax > 0.f ? 127.f / kmax : 0.f;
    float vinv = vmax > 0.f ? 127.f / vmax : 0.f;
    unsigned int klo = 0, khi = 0, vlo = 0, vhi = 0;
    #pragma unroll
    for (int j = 0; j < 4; ++j) {
        klo |= q8(kf[j], kinv) << (8 * j);
        khi |= q8(kf[4 + j], kinv) << (8 * j);
        vlo |= q8(vf[j], vinv) << (8 * j);
        vhi |= q8(vf[4 + j], vinv) << (8 * j);
    }
    *(uint2*)(KV + (size_t)n * 1024 + lane * 8) = make_uint2(klo, khi);
    *(uint2*)(KV + (size_t)n * 1024 + 512 + lane * 8) = make_uint2(vlo, vhi);
    if (lane == 0) sc[n] = make_float2(kmax / 127.f, vmax / 127.f);
}

// Layer 2: one wave per node; lane owns 1 k-ch + 1 v-ch. Row = 128 B (1 line).
__global__ __launch_bounds__(256) void kvpack2_kernel(
    const __hip_bfloat16* __restrict__ Y2, signed char* __restrict__ KV,
    float2* __restrict__ sc) {
    int wid = threadIdx.x >> 6, lane = threadIdx.x & 63;
    int n = blockIdx.x * 4 + wid;
    if (n >= N_NODES) return;
    const __hip_bfloat16* row = Y2 + (size_t)n * Y2W;
    float kf = bf2f(*(const short*)(row + 64 + lane));
    float vf = bf2f(*(const short*)(row + 128 + lane));
    float kmax = fabsf(kf), vmax = fabsf(vf);
    #pragma unroll
    for (int off = 1; off < 64; off <<= 1) {
        kmax = fmaxf(kmax, __shfl_xor(kmax, off));
        vmax = fmaxf(vmax, __shfl_xor(vmax, off));
    }
    float kinv = kmax > 0.f ? 127.f / kmax : 0.f;
    float vinv = vmax > 0.f ? 127.f / vmax : 0.f;
    KV[(size_t)n * 128 + lane] = (signed char)(q8(kf, kinv));
    KV[(size_t)n * 128 + 64 + lane] = (signed char)(q8(vf, vinv));
    if (lane == 0) sc[n] = make_float2(kmax / 127.f, vmax / 127.f);
}

// ---------------------------------------------------------------------------
// MFMA GEMM: C[M,N] = A[M,K] @ B[N,K]^T + bias.  128x128 tile, 4 waves (2x2),
// k-slot XOR swizzle -> conflict-free ds_read_b128.
// ---------------------------------------------------------------------------
template <int K, bool A_F32, bool OUT_BF16>
__global__ __launch_bounds__(256) void gemm_bt(const void* __restrict__ Ap,
                                               const __hip_bfloat16* __restrict__ B,
                                               const float* __restrict__ bias,
                                               void* __restrict__ Cout,
                                               int M, int N, int tiles_n) {
    __shared__ char lds[65536];
    char* ldsA = lds;
    char* ldsB = lds + 32768;
    int tid = threadIdx.x;
    int bm = blockIdx.x / tiles_n, bn = blockIdx.x % tiles_n;
    int w = tid >> 6, lane = tid & 63;
    int wr = (w >> 1) * 64, wc = (w & 1) * 64;
    int lrow = lane & 15, lk = lane >> 4;
    floatx4 acc[4][4] = {};

    for (int kt = 0; kt < K / 128; ++kt) {
        if (kt) __syncthreads();
        #pragma unroll
        for (int it = 0; it < 8; ++it) {
            int s = it * 256 + tid;
            int row = s >> 4, kslot = s & 15;
            int phys = ((kslot ^ (row & 15)) << 4);
            int gr = bm * 128 + row;
            if (gr > M - 1) gr = M - 1;
            short8 va;
            if (A_F32) {
                const float* Af = (const float*)Ap;
                float4 x0 = *(const float4*)(Af + (size_t)gr * K + kt * 128 + kslot * 8);
                float4 x1 = *(const float4*)(Af + (size_t)gr * K + kt * 128 + kslot * 8 + 4);
                va[0] = f2bf(x0.x); va[1] = f2bf(x0.y); va[2] = f2bf(x0.z); va[3] = f2bf(x0.w);
                va[4] = f2bf(x1.x); va[5] = f2bf(x1.y); va[6] = f2bf(x1.z); va[7] = f2bf(x1.w);
            } else {
                const __hip_bfloat16* Ab = (const __hip_bfloat16*)Ap;
                va = *(const short8*)(Ab + (size_t)gr * K + kt * 128 + kslot * 8);
            }
            *(short8*)(ldsA + row * 256 + phys) = va;
            int gc = bn * 128 + row;
            if (gc > N - 1) gc = N - 1;
            short8 vb = *(const short8*)(B + (size_t)gc * K + kt * 128 + kslot * 8);
            *(short8*)(ldsB + row * 256 + phys) = vb;
        }
        __syncthreads();
        #pragma unroll
        for (int ks = 0; ks < 4; ++ks) {
            short8 af[4], bfr[4];
            #pragma unroll
            for (int m = 0; m < 4; ++m) {
                int r = wr + m * 16 + lrow;
                int kslot = ks * 4 + lk;
                af[m] = *(const short8*)(ldsA + r * 256 + ((kslot ^ (r & 15)) << 4));
            }
            #pragma unroll
            for (int n = 0; n < 4; ++n) {
                int c = wc + n * 16 + lrow;
                int kslot = ks * 4 + lk;
                bfr[n] = *(const short8*)(ldsB + c * 256 + ((kslot ^ (c & 15)) << 4));
            }
            #pragma unroll
            for (int m = 0; m < 4; ++m)
                #pragma unroll
                for (int n = 0; n < 4; ++n)
                    acc[m][n] = __builtin_amdgcn_mfma_f32_16x16x32_bf16(af[m], bfr[n], acc[m][n], 0, 0, 0);
        }
    }

    #pragma unroll
    for (int m = 0; m < 4; ++m) {
        #pragma unroll
        for (int j = 0; j < 4; ++j) {
            int r = bm * 128 + wr + m * 16 + lk * 4 + j;
            if (r >= M) continue;
            #pragma unroll
            for (int n = 0; n < 4; ++n) {
                int gc = bn * 128 + wc + n * 16 + lrow;
                if (gc >= N) continue;
                float v = acc[m][n][j] + bias[gc];
                if (OUT_BF16)
                    ((__hip_bfloat16*)Cout)[(size_t)r * N + gc] = __float2bfloat16(v);
                else
                    ((float*)Cout)[(size_t)r * N + gc] = v;
            }
        }
    }
}

// ---------------------------------------------------------------------------
// Layer-1 attention: one wave per dst; lane owns 8 channels (c0 = lane*8),
// head = lane/16; 16-lane-group softmax reduce; int8 k/v gathers.
// ---------------------------------------------------------------------------
__global__ __launch_bounds__(256) void attn1_kernel(
    const __hip_bfloat16* __restrict__ Y1, const signed char* __restrict__ KV1,
    const float2* __restrict__ sc1, const float* __restrict__ eap,
    const int* __restrict__ srcs, const int* __restrict__ rowptr,
    const float* __restrict__ We1, __hip_bfloat16* __restrict__ hb) {
    int wid = threadIdx.x >> 6, lane = threadIdx.x & 63;
    int dst = blockIdx.x * 4 + wid;
    if (dst >= N_NODES) return;
    int c0 = lane * 8;
    int hh = lane >> 4;
    int d0 = (lane & 15) * 2;
    const size_t rowb = (size_t)dst * Y1W;
    short8 qv = *(const short8*)(Y1 + rowb + c0);
    float q[8];
    #pragma unroll
    for (int j = 0; j < 8; ++j) q[j] = bf2f(qv[j]);
    const __hip_bfloat16* pp = Y1 + rowb + 2048 + hh * 32 + d0;
    float pA = __bfloat162float(pp[0]);
    float pB = __bfloat162float(pp[1]);

    float acc[8] = {0.f, 0.f, 0.f, 0.f, 0.f, 0.f, 0.f, 0.f};
    float t0 = 0.f, t1 = 0.f, denom = 0.f;
    int beg = rowptr[dst], end = rowptr[dst + 1];

    auto proc = [&](uint2 ku, uint2 vu, float2 sc, float ea0, float ea1) {
        float sdot = 0.f;
        #pragma unroll
        for (int c = 0; c < 4; ++c) sdot += q[c] * i8tof(ku.x, c);
        #pragma unroll
        for (int c = 0; c < 4; ++c) sdot += q[4 + c] * i8tof(ku.y, c);
        float s = sdot * sc.x + pA * ea0 + pB * ea1;  // sc.x wave-uniform
        s += __shfl_xor(s, 1);
        s += __shfl_xor(s, 2);
        s += __shfl_xor(s, 4);
        s += __shfl_xor(s, 8);
        float wgt = __expf(s * 0.08838834764831845f);  // 1/sqrt(128)
        denom += wgt;
        float wv = wgt * sc.y;
        #pragma unroll
        for (int c = 0; c < 4; ++c) acc[c] += wv * i8tof(vu.x, c);
        #pragma unroll
        for (int c = 0; c < 4; ++c) acc[4 + c] += wv * i8tof(vu.y, c);
        t0 += wgt * ea0;
        t1 += wgt * ea1;
    };

    int i = beg;
    for (; i + 2 <= end; i += 2) {
        int sA = srcs[i], sB = srcs[i + 1];
        const signed char* ka = KV1 + (size_t)sA * 1024 + c0;
        const signed char* kb = KV1 + (size_t)sB * 1024 + c0;
        uint2 kA = *(const uint2*)ka;
        uint2 kB = *(const uint2*)kb;
        uint2 vA = *(const uint2*)(ka + 512);
        uint2 vB = *(const uint2*)(kb + 512);
        float2 scA = sc1[sA], scB = sc1[sB];
        float2 fA = *(const float2*)(eap + (size_t)i * 32 + d0);
        float2 fB = *(const float2*)(eap + (size_t)(i + 1) * 32 + d0);
        proc(kA, vA, scA, fA.x, fA.y);
        proc(kB, vB, scB, fB.x, fB.y);
    }
    if (i < end) {
        int sA = srcs[i];
        const signed char* ka = KV1 + (size_t)sA * 1024 + c0;
        uint2 kA = *(const uint2*)ka;
        uint2 vA = *(const uint2*)(ka + 512);
        float2 fA = *(const float2*)(eap + (size_t)i * 32 + d0);
        proc(kA, vA, sc1[sA], fA.x, fA.y);
    }

    // gather this head's t[0..31] from the 16-lane group
    float tt[32];
    int gbase = lane & 48;
    #pragma unroll
    for (int d = 0; d < 32; ++d)
        tt[d] = __shfl((d & 1) ? t1 : t0, gbase + (d >> 1));
    float inv = (end > beg) ? 1.f / denom : 0.f;
    short8 sv = *(const short8*)(Y1 + rowb + 1536 + c0);
    short8 hv;
    #pragma unroll
    for (int j = 0; j < 8; ++j) {
        const float4* wr = (const float4*)(We1 + (size_t)(c0 + j) * 32);
        float sum = 0.f;
        #pragma unroll
        for (int d4 = 0; d4 < 8; ++d4) {
            float4 w4 = wr[d4];
            sum += w4.x * tt[d4 * 4] + w4.y * tt[d4 * 4 + 1]
                 + w4.z * tt[d4 * 4 + 2] + w4.w * tt[d4 * 4 + 3];
        }
        float v = (acc[j] + sum) * inv + bf2f(sv[j]);
        hv[j] = f2bf(v > 0.f ? v : 0.f);
    }
    *(short8*)(hb + (size_t)dst * D1 + c0) = hv;
}

// ---------------------------------------------------------------------------
// Layer-2 attention: one wave per dst, 1 head, C=64; int8 k/v in 1 line/node.
// ---------------------------------------------------------------------------
__global__ __launch_bounds__(256) void attn2_kernel(
    const __hip_bfloat16* __restrict__ Y2, const signed char* __restrict__ KV2,
    const float2* __restrict__ sc2, const float* __restrict__ eap,
    const int* __restrict__ srcs, const int* __restrict__ rowptr,
    const float* __restrict__ We2, float* __restrict__ zout) {
    int wid = threadIdx.x >> 6, lane = threadIdx.x & 63;
    int dst = blockIdx.x * 4 + wid;
    if (dst >= N_NODES) return;
    const size_t rowb = (size_t)dst * Y2W;
    float qv = __bfloat162float(Y2[rowb + lane]);
    float pv = (lane < 32) ? __bfloat162float(Y2[rowb + 256 + lane]) : 0.f;
    float acc = 0.f, t = 0.f, denom = 0.f;
    int beg = rowptr[dst], end = rowptr[dst + 1];

    auto proc = [&](float kq, float vq, float2 sc, float eav) {
        float s = qv * kq * sc.x + pv * eav;
        s += __shfl_xor(s, 1);
        s += __shfl_xor(s, 2);
        s += __shfl_xor(s, 4);
        s += __shfl_xor(s, 8);
        s += __shfl_xor(s, 16);
        s += __shfl_xor(s, 32);
        float wgt = __expf(s * 0.125f);  // 1/sqrt(64)
        denom += wgt;
        acc += wgt * sc.y * vq;
        t += wgt * eav;
    };

    int i = beg;
    for (; i + 2 <= end; i += 2) {
        int sA = srcs[i], sB = srcs[i + 1];
        const signed char* ra = KV2 + (size_t)sA * 128;
        const signed char* rb = KV2 + (size_t)sB * 128;
        float kA = (float)ra[lane], kB = (float)rb[lane];
        float vA = (float)ra[64 + lane], vB = (float)rb[64 + lane];
        float2 scA = sc2[sA], scB = sc2[sB];
        float eA = (lane < 32) ? eap[(size_t)i * 32 + lane] : 0.f;
        float eB = (lane < 32) ? eap[(size_t)(i + 1) * 32 + lane] : 0.f;
        proc(kA, vA, scA, eA);
        proc(kB, vB, scB, eB);
    }
    if (i < end) {
        int sA = srcs[i];
        const signed char* ra = KV2 + (size_t)sA * 128;
        proc((float)ra[lane], (float)ra[64 + lane], sc2[sA],
             (lane < 32) ? eap[(size_t)i * 32 + lane] : 0.f);
    }

    float tt[32];
    #pragma unroll
    for (int dd = 0; dd < 32; ++dd) tt[dd] = __shfl(t, dd);
    float inv = (end > beg) ? 1.f / denom : 0.f;
    const float4* wr = (const float4*)(We2 + (size_t)lane * 32);
    float sum = 0.f;
    #pragma unroll
    for (int d4 = 0; d4 < 8; ++d4) {
        float4 w4 = wr[d4];
        sum += w4.x * tt[d4 * 4] + w4.y * tt[d4 * 4 + 1]
             + w4.z * tt[d4 * 4 + 2] + w4.w * tt[d4 * 4 + 3];
    }
    zout[(size_t)dst * D2 + lane] =
        (acc + sum) * inv + __bfloat162float(Y2[rowb + 192 + lane]);
}

// ---------------------------------------------------------------------------
extern "C" void kernel_launch(void* const* d_in, const int* in_sizes, int n_in,
                              void* d_out, int out_size, void* d_ws, size_t ws_size,
                              hipStream_t stream) {
    const float* x   = (const float*)d_in[0];
    const int*   ei  = (const int*)d_in[1];
    const float* ea  = (const float*)d_in[2];
    const float* Wq1 = (const float*)d_in[3];  const float* bq1 = (const float*)d_in[4];
    const float* Wk1 = (const float*)d_in[5];  const float* bk1 = (const float*)d_in[6];
    const float* Wv1 = (const float*)d_in[7];  const float* bv1 = (const float*)d_in[8];
    const float* We1 = (const float*)d_in[9];
    const float* Ws1 = (const float*)d_in[10]; const float* bs1 = (const float*)d_in[11];
    const float* Wq2 = (const float*)d_in[12]; const float* bq2 = (const float*)d_in[13];
    const float* Wk2 = (const float*)d_in[14]; const float* bk2 = (const float*)d_in[15];
    const float* Wv2 = (const float*)d_in[16]; const float* bv2 = (const float*)d_in[17];
    const float* We2 = (const float*)d_in[18];
    const float* Ws2 = (const float*)d_in[19]; const float* bs2 = (const float*)d_in[20];
    float* zout = (float*)d_out;

    char* wsb = (char*)d_ws;
    size_t off = 0;
    auto alloc = [&](size_t bytes) -> void* {
        void* p = wsb + off;
        off += (bytes + 255) & ~(size_t)255;
        return p;
    };
    __hip_bfloat16* Y1  = (__hip_bfloat16*)alloc((size_t)N_NODES * Y1W * 2);
    __hip_bfloat16* hbb = (__hip_bfloat16*)alloc((size_t)N_NODES * D1 * 2);
    __hip_bfloat16* Y2  = (__hip_bfloat16*)alloc((size_t)N_NODES * Y2W * 2);
    signed char*    KV1 = (signed char*)alloc((size_t)N_NODES * 1024);
    float2*         sc1 = (float2*)alloc((size_t)N_NODES * 8);
    signed char*    KV2 = (signed char*)alloc((size_t)N_NODES * 128);
    float2*         sc2 = (float2*)alloc((size_t)N_NODES * 8);
    __hip_bfloat16* W1b = (__hip_bfloat16*)alloc((size_t)2176 * 128 * 2);
    float*          b1  = (float*)alloc(2176 * 4);
    __hip_bfloat16* W2b = (__hip_bfloat16*)alloc((size_t)288 * 512 * 2);
    float*          b2  = (float*)alloc(288 * 4);
    int* deg    = (int*)alloc((size_t)N_NODES * 4);
    int* cursor = (int*)alloc((size_t)N_NODES * 4);
    int* rowptr = (int*)alloc((size_t)(N_NODES + 1) * 4);
    int* srcs   = (int*)alloc((size_t)N_EDGES * 4);
    int* eid    = (int*)alloc((size_t)N_EDGES * 4);
    float* eap  = (float*)alloc((size_t)N_EDGES * 32 * 4);

    hipMemsetAsync(deg, 0, (size_t)N_NODES * 4, stream);
    hipMemsetAsync(cursor, 0, (size_t)N_NODES * 4, stream);

    // CSR build + edge-attr permutation
    hist_kernel<<<(N_EDGES + 255) / 256, 256, 0, stream>>>(ei, deg);
    scan_kernel<<<1, 1024, 0, stream>>>(deg, rowptr);
    fill_kernel<<<(N_EDGES + 255) / 256, 256, 0, stream>>>(ei, rowptr, cursor, srcs, eid);
    eaperm_kernel<<<(N_EDGES * 32 + 255) / 256, 256, 0, stream>>>(ea, eid, eap);

    // weight prep (P-columns folded in)
    prep1_kernel<<<2176, 128, 0, stream>>>(Wq1, bq1, Wk1, bk1, Wv1, bv1, Ws1, bs1,
                                           We1, W1b, b1);
    prep2_kernel<<<288, 256, 0, stream>>>(Wq2, bq2, Wk2, bk2, Wv2, bv2, Ws2, bs2,
                                          We2, W2b, b2);

    // layer 1: Y1 = x @ W1b^T + b1   (M=20000, N=2176, K=128)
    int tiles_m = (N_NODES + 127) / 128;  // 157
    gemm_bt<128, true, true><<<tiles_m * 17, 256, 0, stream>>>(
        (const void*)x, W1b, b1, (void*)Y1, N_NODES, Y1W, 17);
    kvpack1_kernel<<<(N_NODES + 3) / 4, 256, 0, stream>>>(Y1, KV1, sc1);
    attn1_kernel<<<(N_NODES + 3) / 4, 256, 0, stream>>>(Y1, KV1, sc1, eap, srcs,
                                                        rowptr, We1, hbb);

    // layer 2: Y2 = h @ W2b^T + b2   (M=20000, N=288, K=512), bf16 out
    gemm_bt<512, false, true><<<tiles_m * 3, 256, 0, stream>>>(
        (const void*)hbb, W2b, b2, (void*)Y2, N_NODES, Y2W, 3);
    kvpack2_kernel<<<(N_NODES + 3) / 4, 256, 0, stream>>>(Y2, KV2, sc2);
    attn2_kernel<<<(N_NODES + 3) / 4, 256, 0, stream>>>(Y2, KV2, sc2, eap, srcs,
                                                        rowptr, We2, zout);
}